// Round 6
// baseline (2431.716 us; speedup 1.0000x reference)
//
#include <hip/hip_runtime.h>
#include <hip/hip_bf16.h>
#include <math.h>

// Problem constants
#define BB 64
#define TT 256
#define EE 300
#define DD 600
#define KP 608        // K padded to 19*32 for MFMA
#define HH 512
#define G4 2048
#define LL 9
#define NT (BB*TT)

typedef __attribute__((ext_vector_type(8))) short short8;   // 8 bf16
typedef __attribute__((ext_vector_type(4))) float floatx4;  // MFMA acc

// ---------------- Workspace layout (bytes) ----------------
#define XZF_OFF  ((size_t)0)
#define XZ_BYTES ((size_t)NT * G4 * 2)                  // 67108864
#define XZB_OFF  (XZF_OFF + XZ_BYTES)
#define HSR_OFF  (XZB_OFF + XZ_BYTES)                   // hs region, 33554432
#define HS_BYTES ((size_t)NT * HH * 2)                  // 16777216
#define HSF_OFF  (HSR_OFF)
#define HSB_OFF  (HSR_OFF + HS_BYTES)
// aliases inside hs region (dead before lstm writes hs):
#define XG_OFF   (HSR_OFF)                              // 16384*608*2
#define WKT_OFF  (HSR_OFF + 19922944)                   // 2*2048*608*2
#define WRT_OFF  (HSR_OFF + (size_t)2 * HS_BYTES)       // 2*2048*512*2 = 4194304
#define BK_OFF   (WRT_OFF + 4194304)                    // backup tagged: 524288
#define FAST_OFF (BK_OFF + 524288)                      // fast tagged:   524288
#define EX_BYTES ((size_t)2 * 2 * BB * HH * 4)          // 524288 each
// WdT aliases xz_f (dead after lstm), written post-lstm:
#define WDT_OFF  XZF_OFF                                // 16*1024*2 = 32768

// Output layout (floats)
#define OUT_LOGITS 0
#define OUT_LENS   (BB*TT*LL)
#define OUT_LL     (OUT_LENS + BB)
#define OUT_TAGS   (OUT_LL + BB)

// ---------------------------------------------------------------------------
// Prep 1: gather embeddings -> xg[n][608] bf16 (zero-padded K)
// ---------------------------------------------------------------------------
__global__ __launch_bounds__(256) void prep_xg(
    const int* __restrict__ text, const int* __restrict__ sent,
    const float* __restrict__ wemb, const float* __restrict__ semb,
    __hip_bfloat16* __restrict__ xg)
{
    int n = blockIdx.x;
    int ti = text[n], si = sent[n];
    __hip_bfloat16* o = xg + (size_t)n * KP;
    for (int k = threadIdx.x; k < KP; k += 256) {
        float v = 0.f;
        if (k < EE)      v = wemb[(size_t)ti * EE + k];
        else if (k < DD) v = semb[(size_t)si * EE + (k - EE)];
        o[k] = __float2bfloat16(v);
    }
}

// ---------------------------------------------------------------------------
// Prep 2: LDS-tiled transpose + bf16 convert. W[dir]=[Din][2048] f32 ->
// out[dir]=[2048][Dpad] bf16
// ---------------------------------------------------------------------------
__global__ __launch_bounds__(256) void transpose_w(
    const float* __restrict__ Wf, const float* __restrict__ Wb,
    __hip_bfloat16* __restrict__ outT, int Din, int Dpad)
{
    int dir = blockIdx.z;
    const float* W = dir ? Wb : Wf;
    __hip_bfloat16* o = outT + (size_t)dir * G4 * Dpad;
    int n0 = blockIdx.x * 64, d0 = blockIdx.y * 64;
    __shared__ float tile[64][65];
    int c = threadIdx.x & 63, r4 = threadIdx.x >> 6;
    #pragma unroll
    for (int rr = 0; rr < 64; rr += 4) {
        int d = d0 + rr + r4;
        tile[rr + r4][c] = (d < Din) ? W[(size_t)d * G4 + n0 + c] : 0.f;
    }
    __syncthreads();
    #pragma unroll
    for (int rr = 0; rr < 64; rr += 4) {
        int n = n0 + rr + r4;
        int d = d0 + c;
        if (d < Dpad) o[(size_t)n * Dpad + d] = __float2bfloat16(tile[c][rr + r4]);
    }
}

// ---------------------------------------------------------------------------
// Prep 3 (post-lstm): WdT[16][1024] bf16, WdT[c][k] = Wd[k][c] (c<9 else 0)
// ---------------------------------------------------------------------------
__global__ __launch_bounds__(256) void prep_wdT(
    const float* __restrict__ Wd, __hip_bfloat16* __restrict__ WdT)
{
    for (int i = threadIdx.x + blockIdx.x * 256; i < 16 * 1024; i += gridDim.x * 256) {
        int nn = i >> 10, k = i & 1023;
        WdT[i] = __float2bfloat16(nn < LL ? Wd[(size_t)k * LL + nn] : 0.f);
    }
}

// ---------------------------------------------------------------------------
// Embed GEMM: 128x64 tile, 8 MFMA / 6 frag-loads per kc
// grid (128, 32, 2), block 256 = 4 waves
// ---------------------------------------------------------------------------
__global__ __launch_bounds__(256) void embed_gemm(
    const __hip_bfloat16* __restrict__ xg,
    const __hip_bfloat16* __restrict__ WkT,
    const float* __restrict__ b_f, const float* __restrict__ b_b,
    __hip_bfloat16* __restrict__ xz_f, __hip_bfloat16* __restrict__ xz_b)
{
    int dir = blockIdx.z;
    const __hip_bfloat16* wt = WkT + (size_t)dir * G4 * KP;
    const float* bias = dir ? b_b : b_f;
    __hip_bfloat16* xz = dir ? xz_b : xz_f;

    int n0 = blockIdx.x * 128;
    int c0 = blockIdx.y * 64;
    int wave = threadIdx.x >> 6, lane = threadIdx.x & 63;
    int m0 = (wave & 1) * 64;     // 4 m-tiles
    int nn0 = (wave >> 1) * 32;   // 2 n-tiles
    int lm = lane & 15, lk8 = (lane >> 4) * 8;

    const short8 *ap[4], *bp2[2];
    #pragma unroll
    for (int i = 0; i < 4; ++i)
        ap[i] = (const short8*)(xg + (size_t)(n0 + m0 + i*16 + lm) * KP + lk8);
    #pragma unroll
    for (int i = 0; i < 2; ++i)
        bp2[i] = (const short8*)(wt + (size_t)(c0 + nn0 + i*16 + lm) * KP + lk8);

    floatx4 acc[4][2] = {};
    for (int kc = 0; kc < KP/32; ++kc) {
        short8 a0 = ap[0][kc*4], a1 = ap[1][kc*4], a2 = ap[2][kc*4], a3 = ap[3][kc*4];
        short8 b0 = bp2[0][kc*4], b1 = bp2[1][kc*4];
        acc[0][0] = __builtin_amdgcn_mfma_f32_16x16x32_bf16(a0, b0, acc[0][0], 0,0,0);
        acc[0][1] = __builtin_amdgcn_mfma_f32_16x16x32_bf16(a0, b1, acc[0][1], 0,0,0);
        acc[1][0] = __builtin_amdgcn_mfma_f32_16x16x32_bf16(a1, b0, acc[1][0], 0,0,0);
        acc[1][1] = __builtin_amdgcn_mfma_f32_16x16x32_bf16(a1, b1, acc[1][1], 0,0,0);
        acc[2][0] = __builtin_amdgcn_mfma_f32_16x16x32_bf16(a2, b0, acc[2][0], 0,0,0);
        acc[2][1] = __builtin_amdgcn_mfma_f32_16x16x32_bf16(a2, b1, acc[2][1], 0,0,0);
        acc[3][0] = __builtin_amdgcn_mfma_f32_16x16x32_bf16(a3, b0, acc[3][0], 0,0,0);
        acc[3][1] = __builtin_amdgcn_mfma_f32_16x16x32_bf16(a3, b1, acc[3][1], 0,0,0);
    }

    int lr = (lane >> 4) * 4;
    #pragma unroll
    for (int ni = 0; ni < 2; ++ni) {
        int col = c0 + nn0 + ni*16 + lm;
        float bs = bias[col];
        #pragma unroll
        for (int mi = 0; mi < 4; ++mi) {
            #pragma unroll
            for (int r = 0; r < 4; ++r) {
                int row = n0 + m0 + mi*16 + lr + r;
                xz[(size_t)row * G4 + col] = __float2bfloat16(acc[mi][ni][r] + bs);
            }
        }
    }
}

// ---------------------------------------------------------------------------
// Persistent LSTM. 256 blocks x 256 threads, cooperative.
// Group remap: g = blk&7 (XCD-aligned under round-robin), member = blk>>3.
// Producers DUAL-STORE tagged u64: volatile (sc0, XCD-local L2) to FAST +
// agent-scope to BACKUP (L3, monotone). Consumers spin on FAST (<=24 rounds,
// wave-uniform), fall back to BACKUP poll (always succeeds; sticky-disable
// FAST after 8 failures). Wrong XCD mapping => R5 behavior, never deadlock.
// ---------------------------------------------------------------------------
__global__ __launch_bounds__(256, 1) void lstm_coop(
    const __hip_bfloat16* __restrict__ xz_f, const __hip_bfloat16* __restrict__ xz_b,
    const __hip_bfloat16* __restrict__ WrT,   // [2][2048][512]
    unsigned* __restrict__ bk,                // backup tagged [2][2][64][512]
    unsigned* __restrict__ fast,              // fast   tagged [2][2][64][512]
    __hip_bfloat16* __restrict__ hs_f, __hip_bfloat16* __restrict__ hs_b)
{
    int blk = blockIdx.x;
    int g = blk & 7;              // group = XCD residue class
    int member = blk >> 3;        // 0..31
    int dir = g >> 2;
    int r0 = (g & 3) * 16;
    int h0 = member * 16;
    int tid = threadIdx.x;
    int gate = tid >> 6, lane = tid & 63;
    int lm = lane & 15, lk8 = (lane >> 4) * 8;

    const __hip_bfloat16* xz = dir ? xz_b : xz_f;
    __hip_bfloat16* hs = dir ? hs_b : hs_f;
    const __hip_bfloat16* wrt = WrT + (size_t)dir * G4 * HH;
    unsigned* bkd = bk + (size_t)dir * 2 * BB * HH;
    unsigned* fsd = fast + (size_t)dir * 2 * BB * HH;

    // persistent weight fragments (gate's 16 cols x full K=512)
    short8 bfrag[16];
    {
        const short8* wp = (const short8*)(wrt + (size_t)(gate*HH + h0 + lm) * HH + lk8);
        #pragma unroll
        for (int kc = 0; kc < 16; ++kc) bfrag[kc] = wp[kc*4];
    }

    __shared__ unsigned short htile[16][520];
    __shared__ float zbuf[4][16][17];

    int er = tid >> 3, ec = (tid & 7) * 2;   // epilogue mapping (tid<128)
    float c0st = 0.f, c1st = 0.f;
    int zr = (lane >> 4) * 4;

    bool fastok = true;
    int fallcnt = 0;

    for (int t = 0; t < TT; ++t) {
        int tok = dir ? (TT - 1 - t) : t;
        size_t soff = (size_t)(t & 1) * BB * HH + (size_t)r0 * HH;
        const unsigned long long pat =
            ((unsigned long long)(unsigned)t << 48) |
            ((unsigned long long)(unsigned)t << 16);

        unsigned long long v[16];
        bool got = false;
        if (fastok) {
            const volatile unsigned long long* fsrc =
                (const volatile unsigned long long*)(fsd + soff);
            for (int spin = 0; spin < 24; ++spin) {
                unsigned long long bad = 0;
                #pragma unroll
                for (int q = 0; q < 16; ++q) v[q] = fsrc[tid + 256*q];
                #pragma unroll
                for (int q = 0; q < 16; ++q)
                    bad |= (v[q] ^ pat) & 0xFFFF0000FFFF0000ULL;
                if (__all(bad == 0)) { got = true; break; }
                __builtin_amdgcn_s_sleep(1);
            }
            if (!got) { if (++fallcnt >= 8) fastok = false; }
        }
        if (!got) {
            const unsigned long long* bsrc = (const unsigned long long*)(bkd + soff);
            for (;;) {
                #pragma unroll
                for (int q = 0; q < 16; ++q)
                    v[q] = __hip_atomic_load(bsrc + tid + 256*q,
                            __ATOMIC_RELAXED, __HIP_MEMORY_SCOPE_AGENT);
                unsigned long long bad = 0;
                #pragma unroll
                for (int q = 0; q < 16; ++q)
                    bad |= (v[q] ^ pat) & 0xFFFF0000FFFF0000ULL;
                if (bad == 0) break;
                __builtin_amdgcn_s_sleep(2);
            }
        }

        // xz prefetch (issued now; completes under stage+MFMA)
        float xzv[4];
        #pragma unroll
        for (int r = 0; r < 4; ++r) {
            int n = (r0 + zr + r) * TT + tok;
            xzv[r] = __bfloat162float(xz[(size_t)n * G4 + gate*HH + h0 + lm]);
        }

        // stage into LDS (strip tags): q -> row q, colpair tid
        #pragma unroll
        for (int q = 0; q < 16; ++q) {
            unsigned lo = (unsigned)(v[q] & 0xffffu);
            unsigned hi = (unsigned)((v[q] >> 32) & 0xffffu);
            *(unsigned*)&htile[q][tid * 2] = lo | (hi << 16);
        }
        __syncthreads();

        floatx4 acc = {};
        #pragma unroll
        for (int kc = 0; kc < 16; ++kc) {
            short8 a = *(const short8*)&htile[lm][kc * 32 + lk8];
            acc = __builtin_amdgcn_mfma_f32_16x16x32_bf16(a, bfrag[kc], acc, 0,0,0);
        }

        #pragma unroll
        for (int r = 0; r < 4; ++r)
            zbuf[gate][zr + r][lm] = acc[r] + xzv[r];
        __syncthreads();

        if (tid < 128) {
            float zi0 = zbuf[0][er][ec],   zi1 = zbuf[0][er][ec+1];
            float zf0 = zbuf[1][er][ec],   zf1 = zbuf[1][er][ec+1];
            float zg0 = zbuf[2][er][ec],   zg1 = zbuf[2][er][ec+1];
            float zo0 = zbuf[3][er][ec],   zo1 = zbuf[3][er][ec+1];
            float si0 = 1.f/(1.f+__expf(-zi0)), si1 = 1.f/(1.f+__expf(-zi1));
            float sf0 = 1.f/(1.f+__expf(-zf0)), sf1 = 1.f/(1.f+__expf(-zf1));
            float so0 = 1.f/(1.f+__expf(-zo0)), so1 = 1.f/(1.f+__expf(-zo1));
            c0st = sf0 * c0st + si0 * tanhf(zg0);
            c1st = sf1 * c1st + si1 * tanhf(zg1);
            float h0v = so0 * tanhf(c0st);
            float h1v = so1 * tanhf(c1st);
            unsigned u0 = (unsigned)__builtin_bit_cast(unsigned short, __float2bfloat16(h0v));
            unsigned u1 = (unsigned)__builtin_bit_cast(unsigned short, __float2bfloat16(h1v));
            unsigned tg = (unsigned)(t + 1) << 16;
            unsigned long long pay =
                ((unsigned long long)(tg | u1) << 32) | (unsigned long long)(tg | u0);
            size_t eoff = (size_t)((t+1) & 1) * BB * HH + (size_t)(r0 + er) * HH + h0 + ec;
            *(volatile unsigned long long*)(fsd + eoff) = pay;   // fast (L2)
            __hip_atomic_store((unsigned long long*)(bkd + eoff), pay,
                               __ATOMIC_RELAXED, __HIP_MEMORY_SCOPE_AGENT); // backup (L3)
            *(unsigned*)(hs + ((size_t)(r0 + er) * TT + tok) * HH + h0 + ec) =
                u0 | (u1 << 16);
        }
    }
}

// ---------------------------------------------------------------------------
// logits via MFMA: 64 tokens/block (4 waves x 16), K=1024, N=16 (9 used)
// ---------------------------------------------------------------------------
__global__ __launch_bounds__(256) void logits_kernel(
    const __hip_bfloat16* __restrict__ hs_f, const __hip_bfloat16* __restrict__ hs_b,
    const __hip_bfloat16* __restrict__ WdT, const float* __restrict__ bd,
    float* __restrict__ out)
{
    int n0 = blockIdx.x * 64;
    int wave = threadIdx.x >> 6, lane = threadIdx.x & 63;
    int lm = lane & 15, lk8 = (lane >> 4) * 8;
    int nw = n0 + wave * 16;
    const short8* af = (const short8*)(hs_f + (size_t)(nw + lm) * HH + lk8);
    const short8* ab = (const short8*)(hs_b + (size_t)(nw + lm) * HH + lk8);
    const short8* bw = (const short8*)(WdT + (size_t)lm * 1024 + lk8);
    floatx4 acc = {};
    #pragma unroll
    for (int kc = 0; kc < 16; ++kc) {
        acc = __builtin_amdgcn_mfma_f32_16x16x32_bf16(af[kc*4], bw[kc*4], acc, 0,0,0);
        acc = __builtin_amdgcn_mfma_f32_16x16x32_bf16(ab[kc*4], bw[(kc+16)*4], acc, 0,0,0);
    }
    if (lm < LL) {
        float bv = bd[lm];
        #pragma unroll
        for (int r = 0; r < 4; ++r) {
            int n = nw + (lane >> 4) * 4 + r;
            out[(size_t)n * LL + lm] = acc[r] + bv;
        }
    }
}

// ---------------------------------------------------------------------------
// CRF: fused lens + log-likelihood + Viterbi. One block/batch, 256 threads.
// Recursion runs wave-synchronous in wave 0 (shfl, zero syncthreads/iter);
// backpointers in LDS; backtrack from LDS.
// ---------------------------------------------------------------------------
__global__ __launch_bounds__(256) void crf_kernel(
    const float* __restrict__ logits, const int* __restrict__ text,
    const int* __restrict__ labels, const float* __restrict__ trans,
    float* __restrict__ out_lens, float* __restrict__ out_ll,
    float* __restrict__ out_tags)
{
    int b = blockIdx.x, tid = threadIdx.x;
    const float* lg = logits + (size_t)b * TT * LL;
    const int* lab = labels + b * TT;

    __shared__ float lgs[TT * LL];
    __shared__ float trs[81];
    __shared__ unsigned char bps[255 * LL + 1];
    __shared__ float partial[256];
    __shared__ int ired[256];
    __shared__ float tagf[TT];

    for (int i = tid; i < TT * LL; i += 256) lgs[i] = lg[i];
    if (tid < 81) trs[tid] = trans[tid];
    ired[tid] = (text[b * TT + tid] != 0) ? 1 : 0;
    __syncthreads();
    for (int s = 128; s > 0; s >>= 1) {
        if (tid < s) ired[tid] += ired[tid + s];
        __syncthreads();
    }
    int len = ired[0];
    if (tid == 0) out_lens[b] = (float)len;

    float up = 0.f;
    for (int t = tid; t < TT; t += 256) {
        float m = (t < len) ? 1.f : 0.f;
        up += m * lgs[t * LL + lab[t]];
        if (t >= 1) up += m * trs[lab[t - 1] * LL + lab[t]];
    }
    partial[tid] = up;
    __syncthreads();
    for (int s = 128; s > 0; s >>= 1) {
        if (tid < s) partial[tid] += partial[tid + s];
        __syncthreads();
    }

    if (tid < 64) {
        int lane = tid;
        int j = (lane < LL) ? lane : 0;
        float trj[LL];
        #pragma unroll
        for (int i = 0; i < LL; ++i) trj[i] = trs[i * LL + j];
        float alpha = lgs[j];
        float vit = alpha;
        for (int t = 1; t < TT; ++t) {
            bool m = t < len;
            float lgv = lgs[t * LL + j];
            float ta[LL];
            float mx = -1e30f, bv = -1e30f; int bi = 0;
            #pragma unroll
            for (int i = 0; i < LL; ++i) {
                float av = __shfl(alpha, i);
                float vv = __shfl(vit, i);
                ta[i] = av + trj[i];
                mx = fmaxf(mx, ta[i]);
                float sv = vv + trj[i];
                if (sv > bv) { bv = sv; bi = i; }
            }
            float s = 0.f;
            #pragma unroll
            for (int i = 0; i < LL; ++i) s += __expf(ta[i] - mx);
            float newa = mx + __logf(s) + lgv;
            float newv = bv + lgv;
            if (m) { alpha = newa; vit = newv; }
            if (lane < LL) bps[(t - 1) * LL + lane] = (unsigned char)(m ? bi : lane);
        }
        float aX[LL], vX[LL];
        #pragma unroll
        for (int i = 0; i < LL; ++i) { aX[i] = __shfl(alpha, i); vX[i] = __shfl(vit, i); }
        if (lane == 0) {
            float mx = -1e30f;
            #pragma unroll
            for (int i = 0; i < LL; ++i) mx = fmaxf(mx, aX[i]);
            float s = 0.f;
            #pragma unroll
            for (int i = 0; i < LL; ++i) s += __expf(aX[i] - mx);
            out_ll[b] = partial[0] - (mx + __logf(s));

            float bvv = vX[0]; int last = 0;
            #pragma unroll
            for (int i = 1; i < LL; ++i) if (vX[i] > bvv) { bvv = vX[i]; last = i; }
            tagf[TT - 1] = (float)last;
            int tg = last;
            for (int s2 = TT - 2; s2 >= 0; --s2) {
                tg = bps[s2 * LL + tg];
                tagf[s2] = (float)tg;
            }
        }
    }
    __syncthreads();
    out_tags[b * TT + tid] = tagf[tid];
}

// ---------------------------------------------------------------------------
extern "C" void kernel_launch(void* const* d_in, const int* in_sizes, int n_in,
                              void* d_out, int out_size, void* d_ws, size_t ws_size,
                              hipStream_t stream)
{
    const int*   text  = (const int*)d_in[0];
    const int*   sent  = (const int*)d_in[1];
    const int*   labels= (const int*)d_in[2];
    const float* wemb  = (const float*)d_in[3];
    const float* semb  = (const float*)d_in[4];
    const float* Wk_f  = (const float*)d_in[5];
    const float* Wr_f  = (const float*)d_in[6];
    const float* b_f   = (const float*)d_in[7];
    const float* Wk_b  = (const float*)d_in[8];
    const float* Wr_b  = (const float*)d_in[9];
    const float* b_b   = (const float*)d_in[10];
    const float* Wd    = (const float*)d_in[11];
    const float* bd    = (const float*)d_in[12];
    const float* trans = (const float*)d_in[13];
    float* out = (float*)d_out;

    char* ws = (char*)d_ws;
    __hip_bfloat16* xz_f = (__hip_bfloat16*)(ws + XZF_OFF);
    __hip_bfloat16* xz_b = (__hip_bfloat16*)(ws + XZB_OFF);
    __hip_bfloat16* hs_f = (__hip_bfloat16*)(ws + HSF_OFF);
    __hip_bfloat16* hs_b = (__hip_bfloat16*)(ws + HSB_OFF);
    __hip_bfloat16* xg   = (__hip_bfloat16*)(ws + XG_OFF);
    __hip_bfloat16* WkT  = (__hip_bfloat16*)(ws + WKT_OFF);
    __hip_bfloat16* WrT  = (__hip_bfloat16*)(ws + WRT_OFF);
    unsigned*       bk   = (unsigned*)(ws + BK_OFF);
    unsigned*       fast = (unsigned*)(ws + FAST_OFF);
    __hip_bfloat16* WdT  = (__hip_bfloat16*)(ws + WDT_OFF);

    prep_xg <<<NT,  256, 0, stream>>>(text, sent, wemb, semb, xg);
    transpose_w<<<dim3(G4/64, (KP+63)/64, 2), 256, 0, stream>>>(Wk_f, Wk_b, WkT, DD, KP);
    transpose_w<<<dim3(G4/64, HH/64, 2),      256, 0, stream>>>(Wr_f, Wr_b, WrT, HH, HH);
    // zero both tagged exchange regions (tag 0 == h(0) = 0)
    hipMemsetAsync(ws + BK_OFF, 0, 2 * EX_BYTES, stream);

    embed_gemm<<<dim3(NT/128, G4/64, 2), 256, 0, stream>>>(
        xg, WkT, b_f, b_b, xz_f, xz_b);

    {
        void* args[] = { (void*)&xz_f, (void*)&xz_b, (void*)&WrT,
                         (void*)&bk, (void*)&fast, (void*)&hs_f, (void*)&hs_b };
        hipLaunchCooperativeKernel((const void*)lstm_coop, dim3(256), dim3(256),
                                   args, 0, stream);
    }

    prep_wdT<<<16, 256, 0, stream>>>(Wd, WdT);   // aliases dead xz_f
    logits_kernel<<<NT/64, 256, 0, stream>>>(hs_f, hs_b, WdT, bd, out + OUT_LOGITS);
    crf_kernel<<<BB, 256, 0, stream>>>(out + OUT_LOGITS, text, labels, trans,
                                       out + OUT_LENS, out + OUT_LL, out + OUT_TAGS);
}

// Round 7
// 1562.092 us; speedup vs baseline: 1.5567x; 1.5567x over previous
//
#include <hip/hip_runtime.h>
#include <hip/hip_bf16.h>
#include <math.h>

// Problem constants
#define BB 64
#define TT 256
#define EE 300
#define DD 600
#define KP 608        // K padded to 19*32 for MFMA
#define HH 512
#define G4 2048
#define LL 9
#define NT (BB*TT)

typedef __attribute__((ext_vector_type(8))) short short8;   // 8 bf16
typedef __attribute__((ext_vector_type(4))) float floatx4;  // MFMA acc

// ---------------- Workspace layout (bytes) ----------------
#define XZF_OFF  ((size_t)0)
#define XZ_BYTES ((size_t)NT * G4 * 2)                  // 67108864
#define XZB_OFF  (XZF_OFF + XZ_BYTES)
#define HSR_OFF  (XZB_OFF + XZ_BYTES)                   // hs region, 33554432
#define HS_BYTES ((size_t)NT * HH * 2)                  // 16777216
#define HSF_OFF  (HSR_OFF)
#define HSB_OFF  (HSR_OFF + HS_BYTES)
// aliases inside hs region (dead before lstm writes hs):
#define XG_OFF   (HSR_OFF)                              // 16384*608*2
#define WKT_OFF  (HSR_OFF + 19922944)                   // 2*2048*608*2
#define WRT_OFF  (HSR_OFF + (size_t)2 * HS_BYTES)       // 2*2048*512*2 = 4194304
#define BK_OFF   (WRT_OFF + 4194304)                    // backup tagged: 524288
#define FAST_OFF (BK_OFF + 524288)                      // fast tagged:   524288
#define EX_BYTES ((size_t)2 * 2 * BB * HH * 4)          // 524288 each
// WdT aliases xz_f (dead after lstm), written post-lstm:
#define WDT_OFF  XZF_OFF                                // 16*1024*2 = 32768

// Output layout (floats)
#define OUT_LOGITS 0
#define OUT_LENS   (BB*TT*LL)
#define OUT_LL     (OUT_LENS + BB)
#define OUT_TAGS   (OUT_LL + BB)

// ---------------------------------------------------------------------------
// Prep 1: gather embeddings -> xg[n][608] bf16 (zero-padded K)
// ---------------------------------------------------------------------------
__global__ __launch_bounds__(256) void prep_xg(
    const int* __restrict__ text, const int* __restrict__ sent,
    const float* __restrict__ wemb, const float* __restrict__ semb,
    __hip_bfloat16* __restrict__ xg)
{
    int n = blockIdx.x;
    int ti = text[n], si = sent[n];
    __hip_bfloat16* o = xg + (size_t)n * KP;
    for (int k = threadIdx.x; k < KP; k += 256) {
        float v = 0.f;
        if (k < EE)      v = wemb[(size_t)ti * EE + k];
        else if (k < DD) v = semb[(size_t)si * EE + (k - EE)];
        o[k] = __float2bfloat16(v);
    }
}

// ---------------------------------------------------------------------------
// Prep 2: LDS-tiled transpose + bf16 convert. W[dir]=[Din][2048] f32 ->
// out[dir]=[2048][Dpad] bf16
// ---------------------------------------------------------------------------
__global__ __launch_bounds__(256) void transpose_w(
    const float* __restrict__ Wf, const float* __restrict__ Wb,
    __hip_bfloat16* __restrict__ outT, int Din, int Dpad)
{
    int dir = blockIdx.z;
    const float* W = dir ? Wb : Wf;
    __hip_bfloat16* o = outT + (size_t)dir * G4 * Dpad;
    int n0 = blockIdx.x * 64, d0 = blockIdx.y * 64;
    __shared__ float tile[64][65];
    int c = threadIdx.x & 63, r4 = threadIdx.x >> 6;
    #pragma unroll
    for (int rr = 0; rr < 64; rr += 4) {
        int d = d0 + rr + r4;
        tile[rr + r4][c] = (d < Din) ? W[(size_t)d * G4 + n0 + c] : 0.f;
    }
    __syncthreads();
    #pragma unroll
    for (int rr = 0; rr < 64; rr += 4) {
        int n = n0 + rr + r4;
        int d = d0 + c;
        if (d < Dpad) o[(size_t)n * Dpad + d] = __float2bfloat16(tile[c][rr + r4]);
    }
}

// ---------------------------------------------------------------------------
// Prep 3 (post-lstm): WdT[16][1024] bf16, WdT[c][k] = Wd[k][c] (c<9 else 0)
// ---------------------------------------------------------------------------
__global__ __launch_bounds__(256) void prep_wdT(
    const float* __restrict__ Wd, __hip_bfloat16* __restrict__ WdT)
{
    for (int i = threadIdx.x + blockIdx.x * 256; i < 16 * 1024; i += gridDim.x * 256) {
        int nn = i >> 10, k = i & 1023;
        WdT[i] = __float2bfloat16(nn < LL ? Wd[(size_t)k * LL + nn] : 0.f);
    }
}

// ---------------------------------------------------------------------------
// Embed GEMM: 128x64 tile, 8 MFMA / 6 frag-loads per kc
// ---------------------------------------------------------------------------
__global__ __launch_bounds__(256) void embed_gemm(
    const __hip_bfloat16* __restrict__ xg,
    const __hip_bfloat16* __restrict__ WkT,
    const float* __restrict__ b_f, const float* __restrict__ b_b,
    __hip_bfloat16* __restrict__ xz_f, __hip_bfloat16* __restrict__ xz_b)
{
    int dir = blockIdx.z;
    const __hip_bfloat16* wt = WkT + (size_t)dir * G4 * KP;
    const float* bias = dir ? b_b : b_f;
    __hip_bfloat16* xz = dir ? xz_b : xz_f;

    int n0 = blockIdx.x * 128;
    int c0 = blockIdx.y * 64;
    int wave = threadIdx.x >> 6, lane = threadIdx.x & 63;
    int m0 = (wave & 1) * 64;
    int nn0 = (wave >> 1) * 32;
    int lm = lane & 15, lk8 = (lane >> 4) * 8;

    const short8 *ap[4], *bp2[2];
    #pragma unroll
    for (int i = 0; i < 4; ++i)
        ap[i] = (const short8*)(xg + (size_t)(n0 + m0 + i*16 + lm) * KP + lk8);
    #pragma unroll
    for (int i = 0; i < 2; ++i)
        bp2[i] = (const short8*)(wt + (size_t)(c0 + nn0 + i*16 + lm) * KP + lk8);

    floatx4 acc[4][2] = {};
    for (int kc = 0; kc < KP/32; ++kc) {
        short8 a0 = ap[0][kc*4], a1 = ap[1][kc*4], a2 = ap[2][kc*4], a3 = ap[3][kc*4];
        short8 b0 = bp2[0][kc*4], b1 = bp2[1][kc*4];
        acc[0][0] = __builtin_amdgcn_mfma_f32_16x16x32_bf16(a0, b0, acc[0][0], 0,0,0);
        acc[0][1] = __builtin_amdgcn_mfma_f32_16x16x32_bf16(a0, b1, acc[0][1], 0,0,0);
        acc[1][0] = __builtin_amdgcn_mfma_f32_16x16x32_bf16(a1, b0, acc[1][0], 0,0,0);
        acc[1][1] = __builtin_amdgcn_mfma_f32_16x16x32_bf16(a1, b1, acc[1][1], 0,0,0);
        acc[2][0] = __builtin_amdgcn_mfma_f32_16x16x32_bf16(a2, b0, acc[2][0], 0,0,0);
        acc[2][1] = __builtin_amdgcn_mfma_f32_16x16x32_bf16(a2, b1, acc[2][1], 0,0,0);
        acc[3][0] = __builtin_amdgcn_mfma_f32_16x16x32_bf16(a3, b0, acc[3][0], 0,0,0);
        acc[3][1] = __builtin_amdgcn_mfma_f32_16x16x32_bf16(a3, b1, acc[3][1], 0,0,0);
    }

    int lr = (lane >> 4) * 4;
    #pragma unroll
    for (int ni = 0; ni < 2; ++ni) {
        int col = c0 + nn0 + ni*16 + lm;
        float bs = bias[col];
        #pragma unroll
        for (int mi = 0; mi < 4; ++mi) {
            #pragma unroll
            for (int r = 0; r < 4; ++r) {
                int row = n0 + m0 + mi*16 + lr + r;
                xz[(size_t)row * G4 + col] = __float2bfloat16(acc[mi][ni][r] + bs);
            }
        }
    }
}

// ---------------------------------------------------------------------------
// sc0 (L1-bypass, L2-served) pipelined load/store primitives.
// Unlike `volatile`, these do NOT get per-access s_waitcnt serialization:
// issue all 16 loads, then ONE vmcnt(0). [R6 post-mortem: volatile = 16
// serialized ~200cyc L2 RTs = ~1.3us/round; this = one RT ~0.1us/round]
// ---------------------------------------------------------------------------
__device__ __forceinline__ void load16_sc0(const unsigned long long* base,
                                           int tid, unsigned long long* v)
{
    #pragma unroll
    for (int q = 0; q < 16; ++q) {
        const unsigned long long* ap = base + tid + 256 * q;
        asm volatile("global_load_dwordx2 %0, %1, off sc0"
                     : "=v"(v[q]) : "v"(ap));
    }
    asm volatile("s_waitcnt vmcnt(0)" ::: "memory");
}

__device__ __forceinline__ void store_sc0(unsigned long long* p,
                                          unsigned long long val)
{
    asm volatile("global_store_dwordx2 %0, %1, off sc0"
                 :: "v"(p), "v"(val) : "memory");
}

// ---------------------------------------------------------------------------
// Persistent LSTM. 256 blocks x 256 threads, cooperative.
// Group remap: g = blk&7 (XCD residue class under round-robin dispatch),
// member = blk>>3. Producers dual-store tagged u64: sc0 (XCD-shared L2) to
// FAST + agent-scope (L3, monotone) to BACKUP. Consumers spin on FAST with
// pipelined sc0 loads (<=16 rounds), fall back to the proven R5 BACKUP poll
// (sticky-disable FAST after 3 failed steps). Wrong mapping => R5 perf,
// never deadlock. WAR-safe over period-2 slots by publish-implies-consumed.
// ---------------------------------------------------------------------------
__global__ __launch_bounds__(256, 1) void lstm_coop(
    const __hip_bfloat16* __restrict__ xz_f, const __hip_bfloat16* __restrict__ xz_b,
    const __hip_bfloat16* __restrict__ WrT,   // [2][2048][512]
    unsigned* __restrict__ bk,                // backup tagged [2][2][64][512]
    unsigned* __restrict__ fast,              // fast   tagged [2][2][64][512]
    __hip_bfloat16* __restrict__ hs_f, __hip_bfloat16* __restrict__ hs_b)
{
    int blk = blockIdx.x;
    int g = blk & 7;              // group = XCD residue class
    int member = blk >> 3;        // 0..31
    int dir = g >> 2;
    int r0 = (g & 3) * 16;
    int h0 = member * 16;
    int tid = threadIdx.x;
    int gate = tid >> 6, lane = tid & 63;
    int lm = lane & 15, lk8 = (lane >> 4) * 8;

    const __hip_bfloat16* xz = dir ? xz_b : xz_f;
    __hip_bfloat16* hs = dir ? hs_b : hs_f;
    const __hip_bfloat16* wrt = WrT + (size_t)dir * G4 * HH;
    unsigned* bkd = bk + (size_t)dir * 2 * BB * HH;
    unsigned* fsd = fast + (size_t)dir * 2 * BB * HH;

    // persistent weight fragments (gate's 16 cols x full K=512)
    short8 bfrag[16];
    {
        const short8* wp = (const short8*)(wrt + (size_t)(gate*HH + h0 + lm) * HH + lk8);
        #pragma unroll
        for (int kc = 0; kc < 16; ++kc) bfrag[kc] = wp[kc*4];
    }

    __shared__ unsigned short htile[16][520];
    __shared__ float zbuf[4][16][17];

    int er = tid >> 3, ec = (tid & 7) * 2;   // epilogue mapping (tid<128)
    float c0st = 0.f, c1st = 0.f;
    int zr = (lane >> 4) * 4;

    bool fastok = true;
    int fallcnt = 0;

    for (int t = 0; t < TT; ++t) {
        int tok = dir ? (TT - 1 - t) : t;
        size_t soff = (size_t)(t & 1) * BB * HH + (size_t)r0 * HH;
        const unsigned long long pat =
            ((unsigned long long)(unsigned)t << 48) |
            ((unsigned long long)(unsigned)t << 16);

        // xz prefetch issued BEFORE the poll (in flight during detection)
        float xzv[4];
        #pragma unroll
        for (int r = 0; r < 4; ++r) {
            int n = (r0 + zr + r) * TT + tok;
            xzv[r] = __bfloat162float(xz[(size_t)n * G4 + gate*HH + h0 + lm]);
        }

        unsigned long long v[16];
        bool got = false;
        if (fastok) {
            const unsigned long long* fsrc = (const unsigned long long*)(fsd + soff);
            for (int spin = 0; spin < 16; ++spin) {
                load16_sc0(fsrc, tid, v);
                unsigned long long bad = 0;
                #pragma unroll
                for (int q = 0; q < 16; ++q)
                    bad |= (v[q] ^ pat) & 0xFFFF0000FFFF0000ULL;
                if (__all(bad == 0)) { got = true; break; }
                __builtin_amdgcn_s_sleep(1);
            }
            if (!got) { if (++fallcnt >= 3) fastok = false; }
        }
        if (!got) {
            const unsigned long long* bsrc = (const unsigned long long*)(bkd + soff);
            for (;;) {
                #pragma unroll
                for (int q = 0; q < 16; ++q)
                    v[q] = __hip_atomic_load(bsrc + tid + 256*q,
                            __ATOMIC_RELAXED, __HIP_MEMORY_SCOPE_AGENT);
                unsigned long long bad = 0;
                #pragma unroll
                for (int q = 0; q < 16; ++q)
                    bad |= (v[q] ^ pat) & 0xFFFF0000FFFF0000ULL;
                if (bad == 0) break;
                __builtin_amdgcn_s_sleep(2);
            }
        }

        // stage into LDS (strip tags): q -> row q, colpair tid
        #pragma unroll
        for (int q = 0; q < 16; ++q) {
            unsigned lo = (unsigned)(v[q] & 0xffffu);
            unsigned hi = (unsigned)((v[q] >> 32) & 0xffffu);
            *(unsigned*)&htile[q][tid * 2] = lo | (hi << 16);
        }
        __syncthreads();

        floatx4 acc = {};
        #pragma unroll
        for (int kc = 0; kc < 16; ++kc) {
            short8 a = *(const short8*)&htile[lm][kc * 32 + lk8];
            acc = __builtin_amdgcn_mfma_f32_16x16x32_bf16(a, bfrag[kc], acc, 0,0,0);
        }

        #pragma unroll
        for (int r = 0; r < 4; ++r)
            zbuf[gate][zr + r][lm] = acc[r] + xzv[r];
        __syncthreads();

        if (tid < 128) {
            float zi0 = zbuf[0][er][ec],   zi1 = zbuf[0][er][ec+1];
            float zf0 = zbuf[1][er][ec],   zf1 = zbuf[1][er][ec+1];
            float zg0 = zbuf[2][er][ec],   zg1 = zbuf[2][er][ec+1];
            float zo0 = zbuf[3][er][ec],   zo1 = zbuf[3][er][ec+1];
            float si0 = 1.f/(1.f+__expf(-zi0)), si1 = 1.f/(1.f+__expf(-zi1));
            float sf0 = 1.f/(1.f+__expf(-zf0)), sf1 = 1.f/(1.f+__expf(-zf1));
            float so0 = 1.f/(1.f+__expf(-zo0)), so1 = 1.f/(1.f+__expf(-zo1));
            c0st = sf0 * c0st + si0 * tanhf(zg0);
            c1st = sf1 * c1st + si1 * tanhf(zg1);
            float h0v = so0 * tanhf(c0st);
            float h1v = so1 * tanhf(c1st);
            unsigned u0 = (unsigned)__builtin_bit_cast(unsigned short, __float2bfloat16(h0v));
            unsigned u1 = (unsigned)__builtin_bit_cast(unsigned short, __float2bfloat16(h1v));
            unsigned tg = (unsigned)(t + 1) << 16;
            unsigned long long pay =
                ((unsigned long long)(tg | u1) << 32) | (unsigned long long)(tg | u0);
            size_t eoff = (size_t)((t+1) & 1) * BB * HH + (size_t)(r0 + er) * HH + h0 + ec;
            store_sc0((unsigned long long*)(fsd + eoff), pay);          // fast (L2)
            __hip_atomic_store((unsigned long long*)(bkd + eoff), pay,
                               __ATOMIC_RELAXED, __HIP_MEMORY_SCOPE_AGENT); // backup (L3)
            *(unsigned*)(hs + ((size_t)(r0 + er) * TT + tok) * HH + h0 + ec) =
                u0 | (u1 << 16);
        }
    }
}

// ---------------------------------------------------------------------------
// logits via MFMA: 64 tokens/block (4 waves x 16), K=1024, N=16 (9 used)
// ---------------------------------------------------------------------------
__global__ __launch_bounds__(256) void logits_kernel(
    const __hip_bfloat16* __restrict__ hs_f, const __hip_bfloat16* __restrict__ hs_b,
    const __hip_bfloat16* __restrict__ WdT, const float* __restrict__ bd,
    float* __restrict__ out)
{
    int n0 = blockIdx.x * 64;
    int wave = threadIdx.x >> 6, lane = threadIdx.x & 63;
    int lm = lane & 15, lk8 = (lane >> 4) * 8;
    int nw = n0 + wave * 16;
    const short8* af = (const short8*)(hs_f + (size_t)(nw + lm) * HH + lk8);
    const short8* ab = (const short8*)(hs_b + (size_t)(nw + lm) * HH + lk8);
    const short8* bw = (const short8*)(WdT + (size_t)lm * 1024 + lk8);
    floatx4 acc = {};
    #pragma unroll
    for (int kc = 0; kc < 16; ++kc) {
        acc = __builtin_amdgcn_mfma_f32_16x16x32_bf16(af[kc*4], bw[kc*4], acc, 0,0,0);
        acc = __builtin_amdgcn_mfma_f32_16x16x32_bf16(ab[kc*4], bw[(kc+16)*4], acc, 0,0,0);
    }
    if (lm < LL) {
        float bv = bd[lm];
        #pragma unroll
        for (int r = 0; r < 4; ++r) {
            int n = nw + (lane >> 4) * 4 + r;
            out[(size_t)n * LL + lm] = acc[r] + bv;
        }
    }
}

// ---------------------------------------------------------------------------
// CRF: fused lens + log-likelihood + Viterbi. One block/batch, 256 threads.
// Recursion wave-synchronous in wave 0 (shfl, zero syncthreads/iter).
// ---------------------------------------------------------------------------
__global__ __launch_bounds__(256) void crf_kernel(
    const float* __restrict__ logits, const int* __restrict__ text,
    const int* __restrict__ labels, const float* __restrict__ trans,
    float* __restrict__ out_lens, float* __restrict__ out_ll,
    float* __restrict__ out_tags)
{
    int b = blockIdx.x, tid = threadIdx.x;
    const float* lg = logits + (size_t)b * TT * LL;
    const int* lab = labels + b * TT;

    __shared__ float lgs[TT * LL];
    __shared__ float trs[81];
    __shared__ unsigned char bps[255 * LL + 1];
    __shared__ float partial[256];
    __shared__ int ired[256];
    __shared__ float tagf[TT];

    for (int i = tid; i < TT * LL; i += 256) lgs[i] = lg[i];
    if (tid < 81) trs[tid] = trans[tid];
    ired[tid] = (text[b * TT + tid] != 0) ? 1 : 0;
    __syncthreads();
    for (int s = 128; s > 0; s >>= 1) {
        if (tid < s) ired[tid] += ired[tid + s];
        __syncthreads();
    }
    int len = ired[0];
    if (tid == 0) out_lens[b] = (float)len;

    float up = 0.f;
    for (int t = tid; t < TT; t += 256) {
        float m = (t < len) ? 1.f : 0.f;
        up += m * lgs[t * LL + lab[t]];
        if (t >= 1) up += m * trs[lab[t - 1] * LL + lab[t]];
    }
    partial[tid] = up;
    __syncthreads();
    for (int s = 128; s > 0; s >>= 1) {
        if (tid < s) partial[tid] += partial[tid + s];
        __syncthreads();
    }

    if (tid < 64) {
        int lane = tid;
        int j = (lane < LL) ? lane : 0;
        float trj[LL];
        #pragma unroll
        for (int i = 0; i < LL; ++i) trj[i] = trs[i * LL + j];
        float alpha = lgs[j];
        float vit = alpha;
        for (int t = 1; t < TT; ++t) {
            bool m = t < len;
            float lgv = lgs[t * LL + j];
            float ta[LL];
            float mx = -1e30f, bv = -1e30f; int bi = 0;
            #pragma unroll
            for (int i = 0; i < LL; ++i) {
                float av = __shfl(alpha, i);
                float vv = __shfl(vit, i);
                ta[i] = av + trj[i];
                mx = fmaxf(mx, ta[i]);
                float sv = vv + trj[i];
                if (sv > bv) { bv = sv; bi = i; }
            }
            float s = 0.f;
            #pragma unroll
            for (int i = 0; i < LL; ++i) s += __expf(ta[i] - mx);
            float newa = mx + __logf(s) + lgv;
            float newv = bv + lgv;
            if (m) { alpha = newa; vit = newv; }
            if (lane < LL) bps[(t - 1) * LL + lane] = (unsigned char)(m ? bi : lane);
        }
        float aX[LL], vX[LL];
        #pragma unroll
        for (int i = 0; i < LL; ++i) { aX[i] = __shfl(alpha, i); vX[i] = __shfl(vit, i); }
        if (lane == 0) {
            float mx = -1e30f;
            #pragma unroll
            for (int i = 0; i < LL; ++i) mx = fmaxf(mx, aX[i]);
            float s = 0.f;
            #pragma unroll
            for (int i = 0; i < LL; ++i) s += __expf(aX[i] - mx);
            out_ll[b] = partial[0] - (mx + __logf(s));

            float bvv = vX[0]; int last = 0;
            #pragma unroll
            for (int i = 1; i < LL; ++i) if (vX[i] > bvv) { bvv = vX[i]; last = i; }
            tagf[TT - 1] = (float)last;
            int tg = last;
            for (int s2 = TT - 2; s2 >= 0; --s2) {
                tg = bps[s2 * LL + tg];
                tagf[s2] = (float)tg;
            }
        }
    }
    __syncthreads();
    out_tags[b * TT + tid] = tagf[tid];
}

// ---------------------------------------------------------------------------
extern "C" void kernel_launch(void* const* d_in, const int* in_sizes, int n_in,
                              void* d_out, int out_size, void* d_ws, size_t ws_size,
                              hipStream_t stream)
{
    const int*   text  = (const int*)d_in[0];
    const int*   sent  = (const int*)d_in[1];
    const int*   labels= (const int*)d_in[2];
    const float* wemb  = (const float*)d_in[3];
    const float* semb  = (const float*)d_in[4];
    const float* Wk_f  = (const float*)d_in[5];
    const float* Wr_f  = (const float*)d_in[6];
    const float* b_f   = (const float*)d_in[7];
    const float* Wk_b  = (const float*)d_in[8];
    const float* Wr_b  = (const float*)d_in[9];
    const float* b_b   = (const float*)d_in[10];
    const float* Wd    = (const float*)d_in[11];
    const float* bd    = (const float*)d_in[12];
    const float* trans = (const float*)d_in[13];
    float* out = (float*)d_out;

    char* ws = (char*)d_ws;
    __hip_bfloat16* xz_f = (__hip_bfloat16*)(ws + XZF_OFF);
    __hip_bfloat16* xz_b = (__hip_bfloat16*)(ws + XZB_OFF);
    __hip_bfloat16* hs_f = (__hip_bfloat16*)(ws + HSF_OFF);
    __hip_bfloat16* hs_b = (__hip_bfloat16*)(ws + HSB_OFF);
    __hip_bfloat16* xg   = (__hip_bfloat16*)(ws + XG_OFF);
    __hip_bfloat16* WkT  = (__hip_bfloat16*)(ws + WKT_OFF);
    __hip_bfloat16* WrT  = (__hip_bfloat16*)(ws + WRT_OFF);
    unsigned*       bk   = (unsigned*)(ws + BK_OFF);
    unsigned*       fast = (unsigned*)(ws + FAST_OFF);
    __hip_bfloat16* WdT  = (__hip_bfloat16*)(ws + WDT_OFF);

    prep_xg <<<NT,  256, 0, stream>>>(text, sent, wemb, semb, xg);
    transpose_w<<<dim3(G4/64, (KP+63)/64, 2), 256, 0, stream>>>(Wk_f, Wk_b, WkT, DD, KP);
    transpose_w<<<dim3(G4/64, HH/64, 2),      256, 0, stream>>>(Wr_f, Wr_b, WrT, HH, HH);
    // zero both tagged exchange regions (tag 0 == h(0) = 0)
    hipMemsetAsync(ws + BK_OFF, 0, 2 * EX_BYTES, stream);

    embed_gemm<<<dim3(NT/128, G4/64, 2), 256, 0, stream>>>(
        xg, WkT, b_f, b_b, xz_f, xz_b);

    {
        void* args[] = { (void*)&xz_f, (void*)&xz_b, (void*)&WrT,
                         (void*)&bk, (void*)&fast, (void*)&hs_f, (void*)&hs_b };
        hipLaunchCooperativeKernel((const void*)lstm_coop, dim3(256), dim3(256),
                                   args, 0, stream);
    }

    prep_wdT<<<16, 256, 0, stream>>>(Wd, WdT);   // aliases dead xz_f
    logits_kernel<<<NT/64, 256, 0, stream>>>(hs_f, hs_b, WdT, bd, out + OUT_LOGITS);
    crf_kernel<<<BB, 256, 0, stream>>>(out + OUT_LOGITS, text, labels, trans,
                                       out + OUT_LENS, out + OUT_LL, out + OUT_TAGS);
}

// Round 8
// 1430.388 us; speedup vs baseline: 1.7000x; 1.0921x over previous
//
#include <hip/hip_runtime.h>
#include <hip/hip_bf16.h>
#include <math.h>

// Problem constants
#define BB 64
#define TT 256
#define EE 300
#define DD 600
#define KP 608        // K padded to 19*32 for MFMA
#define HH 512
#define G4 2048
#define LL 9
#define NT (BB*TT)

typedef __attribute__((ext_vector_type(8))) short short8;   // 8 bf16
typedef __attribute__((ext_vector_type(4))) float floatx4;  // MFMA acc

// ---------------- Workspace layout (bytes) ----------------
#define XZF_OFF  ((size_t)0)
#define XZ_BYTES ((size_t)NT * G4 * 2)                  // 67108864
#define XZB_OFF  (XZF_OFF + XZ_BYTES)
#define HSR_OFF  (XZB_OFF + XZ_BYTES)                   // hs region, 33554432
#define HS_BYTES ((size_t)NT * HH * 2)                  // 16777216
#define HSF_OFF  (HSR_OFF)
#define HSB_OFF  (HSR_OFF + HS_BYTES)
// aliases inside hs region (dead before lstm writes hs):
#define XG_OFF   (HSR_OFF)                              // 16384*608*2
#define WKT_OFF  (HSR_OFF + 19922944)                   // 2*2048*608*2
#define WRT_OFF  (HSR_OFF + (size_t)2 * HS_BYTES)       // 2*2048*512*2 = 4194304
#define BK_OFF   (WRT_OFF + 4194304)                    // backup tagged: 524288
#define FAST_OFF (BK_OFF + 524288)                      // fast tagged:   524288
#define EX_BYTES ((size_t)2 * 2 * BB * HH * 4)          // 524288 each
#define FLAGS_OFF (FAST_OFF + 524288)                   // 8 groups * 32 u32 = 1024
// WdT aliases xz_f (dead after lstm), written post-lstm:
#define WDT_OFF  XZF_OFF                                // 16*1024*2 = 32768

// Output layout (floats)
#define OUT_LOGITS 0
#define OUT_LENS   (BB*TT*LL)
#define OUT_LL     (OUT_LENS + BB)
#define OUT_TAGS   (OUT_LL + BB)

// ---------------------------------------------------------------------------
// Prep 1: gather embeddings -> xg[n][608] bf16 (zero-padded K)
// ---------------------------------------------------------------------------
__global__ __launch_bounds__(256) void prep_xg(
    const int* __restrict__ text, const int* __restrict__ sent,
    const float* __restrict__ wemb, const float* __restrict__ semb,
    __hip_bfloat16* __restrict__ xg)
{
    int n = blockIdx.x;
    int ti = text[n], si = sent[n];
    __hip_bfloat16* o = xg + (size_t)n * KP;
    for (int k = threadIdx.x; k < KP; k += 256) {
        float v = 0.f;
        if (k < EE)      v = wemb[(size_t)ti * EE + k];
        else if (k < DD) v = semb[(size_t)si * EE + (k - EE)];
        o[k] = __float2bfloat16(v);
    }
}

// ---------------------------------------------------------------------------
// Prep 2: LDS-tiled transpose + bf16 convert. W[dir]=[Din][2048] f32 ->
// out[dir]=[2048][Dpad] bf16
// ---------------------------------------------------------------------------
__global__ __launch_bounds__(256) void transpose_w(
    const float* __restrict__ Wf, const float* __restrict__ Wb,
    __hip_bfloat16* __restrict__ outT, int Din, int Dpad)
{
    int dir = blockIdx.z;
    const float* W = dir ? Wb : Wf;
    __hip_bfloat16* o = outT + (size_t)dir * G4 * Dpad;
    int n0 = blockIdx.x * 64, d0 = blockIdx.y * 64;
    __shared__ float tile[64][65];
    int c = threadIdx.x & 63, r4 = threadIdx.x >> 6;
    #pragma unroll
    for (int rr = 0; rr < 64; rr += 4) {
        int d = d0 + rr + r4;
        tile[rr + r4][c] = (d < Din) ? W[(size_t)d * G4 + n0 + c] : 0.f;
    }
    __syncthreads();
    #pragma unroll
    for (int rr = 0; rr < 64; rr += 4) {
        int n = n0 + rr + r4;
        int d = d0 + c;
        if (d < Dpad) o[(size_t)n * Dpad + d] = __float2bfloat16(tile[c][rr + r4]);
    }
}

// ---------------------------------------------------------------------------
// Prep 3 (post-lstm): WdT[16][1024] bf16, WdT[c][k] = Wd[k][c] (c<9 else 0)
// ---------------------------------------------------------------------------
__global__ __launch_bounds__(256) void prep_wdT(
    const float* __restrict__ Wd, __hip_bfloat16* __restrict__ WdT)
{
    for (int i = threadIdx.x + blockIdx.x * 256; i < 16 * 1024; i += gridDim.x * 256) {
        int nn = i >> 10, k = i & 1023;
        WdT[i] = __float2bfloat16(nn < LL ? Wd[(size_t)k * LL + nn] : 0.f);
    }
}

// ---------------------------------------------------------------------------
// Embed GEMM: 128x64 tile, 8 MFMA / 6 frag-loads per kc
// ---------------------------------------------------------------------------
__global__ __launch_bounds__(256) void embed_gemm(
    const __hip_bfloat16* __restrict__ xg,
    const __hip_bfloat16* __restrict__ WkT,
    const float* __restrict__ b_f, const float* __restrict__ b_b,
    __hip_bfloat16* __restrict__ xz_f, __hip_bfloat16* __restrict__ xz_b)
{
    int dir = blockIdx.z;
    const __hip_bfloat16* wt = WkT + (size_t)dir * G4 * KP;
    const float* bias = dir ? b_b : b_f;
    __hip_bfloat16* xz = dir ? xz_b : xz_f;

    int n0 = blockIdx.x * 128;
    int c0 = blockIdx.y * 64;
    int wave = threadIdx.x >> 6, lane = threadIdx.x & 63;
    int m0 = (wave & 1) * 64;
    int nn0 = (wave >> 1) * 32;
    int lm = lane & 15, lk8 = (lane >> 4) * 8;

    const short8 *ap[4], *bp2[2];
    #pragma unroll
    for (int i = 0; i < 4; ++i)
        ap[i] = (const short8*)(xg + (size_t)(n0 + m0 + i*16 + lm) * KP + lk8);
    #pragma unroll
    for (int i = 0; i < 2; ++i)
        bp2[i] = (const short8*)(wt + (size_t)(c0 + nn0 + i*16 + lm) * KP + lk8);

    floatx4 acc[4][2] = {};
    for (int kc = 0; kc < KP/32; ++kc) {
        short8 a0 = ap[0][kc*4], a1 = ap[1][kc*4], a2 = ap[2][kc*4], a3 = ap[3][kc*4];
        short8 b0 = bp2[0][kc*4], b1 = bp2[1][kc*4];
        acc[0][0] = __builtin_amdgcn_mfma_f32_16x16x32_bf16(a0, b0, acc[0][0], 0,0,0);
        acc[0][1] = __builtin_amdgcn_mfma_f32_16x16x32_bf16(a0, b1, acc[0][1], 0,0,0);
        acc[1][0] = __builtin_amdgcn_mfma_f32_16x16x32_bf16(a1, b0, acc[1][0], 0,0,0);
        acc[1][1] = __builtin_amdgcn_mfma_f32_16x16x32_bf16(a1, b1, acc[1][1], 0,0,0);
        acc[2][0] = __builtin_amdgcn_mfma_f32_16x16x32_bf16(a2, b0, acc[2][0], 0,0,0);
        acc[2][1] = __builtin_amdgcn_mfma_f32_16x16x32_bf16(a2, b1, acc[2][1], 0,0,0);
        acc[3][0] = __builtin_amdgcn_mfma_f32_16x16x32_bf16(a3, b0, acc[3][0], 0,0,0);
        acc[3][1] = __builtin_amdgcn_mfma_f32_16x16x32_bf16(a3, b1, acc[3][1], 0,0,0);
    }

    int lr = (lane >> 4) * 4;
    #pragma unroll
    for (int ni = 0; ni < 2; ++ni) {
        int col = c0 + nn0 + ni*16 + lm;
        float bs = bias[col];
        #pragma unroll
        for (int mi = 0; mi < 4; ++mi) {
            #pragma unroll
            for (int r = 0; r < 4; ++r) {
                int row = n0 + m0 + mi*16 + lr + r;
                xz[(size_t)row * G4 + col] = __float2bfloat16(acc[mi][ni][r] + bs);
            }
        }
    }
}

// ---------------------------------------------------------------------------
// sc0 (L1-bypass, L2-served) pipelined primitives
// ---------------------------------------------------------------------------
__device__ __forceinline__ void load16_sc0(const unsigned long long* base,
                                           int tid, unsigned long long* v)
{
    #pragma unroll
    for (int q = 0; q < 16; ++q) {
        const unsigned long long* ap = base + tid + 256 * q;
        asm volatile("global_load_dwordx2 %0, %1, off sc0"
                     : "=v"(v[q]) : "v"(ap));
    }
    asm volatile("s_waitcnt vmcnt(0)" ::: "memory");
}

__device__ __forceinline__ void store_sc0(unsigned long long* p,
                                          unsigned long long val)
{
    asm volatile("global_store_dwordx2 %0, %1, off sc0"
                 :: "v"(p), "v"(val) : "memory");
}

__device__ __forceinline__ unsigned load_u32_sc0(const unsigned* p)
{
    unsigned r;
    asm volatile("global_load_dword %0, %1, off sc0\n\ts_waitcnt vmcnt(0)"
                 : "=v"(r) : "v"(p) : "memory");
    return r;
}

__device__ __forceinline__ void store_u32_sc0(unsigned* p, unsigned v)
{
    asm volatile("global_store_dword %0, %1, off sc0" :: "v"(p), "v"(v) : "memory");
}

// ---------------------------------------------------------------------------
// Persistent LSTM. 256 blocks x 256 threads, cooperative.
// g = blk&7 (XCD residue class — confirmed L2-local by R6/R7 FETCH collapse),
// member = blk>>3. Fast path: (1) SPECULATIVE tagged-data read (1 RT when
// producers ahead); (2) on miss, poll 128B FLAG array (not the 32KB tile —
// fixes R7's L2-bandwidth poll saturation); (3) one final data read.
// Producer: fast+backup+hs stores -> drain barrier -> flag=t+1 (flag implies
// data visible in same L2). Backup (L3, tag-in-data) unchanged: bounded flag
// spins fall back to it; sticky-disable after 3 failed steps. Never deadlocks.
// ---------------------------------------------------------------------------
__global__ __launch_bounds__(256, 1) void lstm_coop(
    const __hip_bfloat16* __restrict__ xz_f, const __hip_bfloat16* __restrict__ xz_b,
    const __hip_bfloat16* __restrict__ WrT,   // [2][2048][512]
    unsigned* __restrict__ bk,                // backup tagged [2][2][64][512]
    unsigned* __restrict__ fast,              // fast   tagged [2][2][64][512]
    unsigned* __restrict__ flags,             // [8 groups][32 members]
    __hip_bfloat16* __restrict__ hs_f, __hip_bfloat16* __restrict__ hs_b)
{
    int blk = blockIdx.x;
    int g = blk & 7;              // group = XCD residue class
    int member = blk >> 3;        // 0..31
    int dir = g >> 2;
    int r0 = (g & 3) * 16;
    int h0 = member * 16;
    int tid = threadIdx.x;
    int gate = tid >> 6, lane = tid & 63;
    int lm = lane & 15, lk8 = (lane >> 4) * 8;

    const __hip_bfloat16* xz = dir ? xz_b : xz_f;
    __hip_bfloat16* hs = dir ? hs_b : hs_f;
    const __hip_bfloat16* wrt = WrT + (size_t)dir * G4 * HH;
    unsigned* bkd = bk + (size_t)dir * 2 * BB * HH;
    unsigned* fsd = fast + (size_t)dir * 2 * BB * HH;
    const unsigned* gfl = flags + (g << 5);
    unsigned* myflag = flags + (g << 5) + member;

    // persistent weight fragments (gate's 16 cols x full K=512)
    short8 bfrag[16];
    {
        const short8* wp = (const short8*)(wrt + (size_t)(gate*HH + h0 + lm) * HH + lk8);
        #pragma unroll
        for (int kc = 0; kc < 16; ++kc) bfrag[kc] = wp[kc*4];
    }

    __shared__ unsigned short htile[16][520];
    __shared__ float zbuf[4][16][17];

    int er = tid >> 3, ec = (tid & 7) * 2;   // epilogue mapping (tid<128)
    float c0st = 0.f, c1st = 0.f;
    int zr = (lane >> 4) * 4;

    bool fastok = true;
    int fallcnt = 0;

    for (int t = 0; t < TT; ++t) {
        int tok = dir ? (TT - 1 - t) : t;
        size_t soff = (size_t)(t & 1) * BB * HH + (size_t)r0 * HH;
        const unsigned long long pat =
            ((unsigned long long)(unsigned)t << 48) |
            ((unsigned long long)(unsigned)t << 16);

        // xz prefetch issued BEFORE detection (in flight during poll)
        float xzv[4];
        #pragma unroll
        for (int r = 0; r < 4; ++r) {
            int n = (r0 + zr + r) * TT + tok;
            xzv[r] = __bfloat162float(xz[(size_t)n * G4 + gate*HH + h0 + lm]);
        }

        unsigned long long v[16];
        bool ok = false;
        if (fastok) {
            const unsigned long long* fsrc = (const unsigned long long*)(fsd + soff);
            // (1) speculative read — tags embedded, 1 RT in the common case
            load16_sc0(fsrc, tid, v);
            unsigned long long bad = 0;
            #pragma unroll
            for (int q = 0; q < 16; ++q)
                bad |= (v[q] ^ pat) & 0xFFFF0000FFFF0000ULL;
            if (__all(bad == 0)) {
                ok = true;
            } else {
                // (2) cheap flag poll: 1 dword/lane/round (128 B/block/round)
                unsigned need = (unsigned)t;
                bool flagok = false;
                for (int spin = 0; spin < 96; ++spin) {
                    unsigned f = load_u32_sc0(gfl + (lane & 31));
                    if (__all(f >= need)) { flagok = true; break; }
                    __builtin_amdgcn_s_sleep(2);
                }
                if (flagok) {
                    // (3) one final data read; flag implies visible in this L2
                    load16_sc0(fsrc, tid, v);
                    bad = 0;
                    #pragma unroll
                    for (int q = 0; q < 16; ++q)
                        bad |= (v[q] ^ pat) & 0xFFFF0000FFFF0000ULL;
                    if (__all(bad == 0)) ok = true;
                }
                if (!ok) { if (++fallcnt >= 3) fastok = false; }
            }
        }
        if (!ok) {
            // proven R5 backup: agent-scope tag-in-data poll at L3
            const unsigned long long* bsrc = (const unsigned long long*)(bkd + soff);
            for (;;) {
                #pragma unroll
                for (int q = 0; q < 16; ++q)
                    v[q] = __hip_atomic_load(bsrc + tid + 256*q,
                            __ATOMIC_RELAXED, __HIP_MEMORY_SCOPE_AGENT);
                unsigned long long bad = 0;
                #pragma unroll
                for (int q = 0; q < 16; ++q)
                    bad |= (v[q] ^ pat) & 0xFFFF0000FFFF0000ULL;
                if (bad == 0) break;
                __builtin_amdgcn_s_sleep(2);
            }
        }

        // stage into LDS (strip tags): q -> row q, colpair tid
        #pragma unroll
        for (int q = 0; q < 16; ++q) {
            unsigned lo = (unsigned)(v[q] & 0xffffu);
            unsigned hi = (unsigned)((v[q] >> 32) & 0xffffu);
            *(unsigned*)&htile[q][tid * 2] = lo | (hi << 16);
        }
        __syncthreads();

        floatx4 acc = {};
        #pragma unroll
        for (int kc = 0; kc < 16; ++kc) {
            short8 a = *(const short8*)&htile[lm][kc * 32 + lk8];
            acc = __builtin_amdgcn_mfma_f32_16x16x32_bf16(a, bfrag[kc], acc, 0,0,0);
        }

        #pragma unroll
        for (int r = 0; r < 4; ++r)
            zbuf[gate][zr + r][lm] = acc[r] + xzv[r];
        __syncthreads();

        if (tid < 128) {
            float zi0 = zbuf[0][er][ec],   zi1 = zbuf[0][er][ec+1];
            float zf0 = zbuf[1][er][ec],   zf1 = zbuf[1][er][ec+1];
            float zg0 = zbuf[2][er][ec],   zg1 = zbuf[2][er][ec+1];
            float zo0 = zbuf[3][er][ec],   zo1 = zbuf[3][er][ec+1];
            float si0 = 1.f/(1.f+__expf(-zi0)), si1 = 1.f/(1.f+__expf(-zi1));
            float sf0 = 1.f/(1.f+__expf(-zf0)), sf1 = 1.f/(1.f+__expf(-zf1));
            float so0 = 1.f/(1.f+__expf(-zo0)), so1 = 1.f/(1.f+__expf(-zo1));
            c0st = sf0 * c0st + si0 * tanhf(zg0);
            c1st = sf1 * c1st + si1 * tanhf(zg1);
            float h0v = so0 * tanhf(c0st);
            float h1v = so1 * tanhf(c1st);
            unsigned u0 = (unsigned)__builtin_bit_cast(unsigned short, __float2bfloat16(h0v));
            unsigned u1 = (unsigned)__builtin_bit_cast(unsigned short, __float2bfloat16(h1v));
            unsigned tg = (unsigned)(t + 1) << 16;
            unsigned long long pay =
                ((unsigned long long)(tg | u1) << 32) | (unsigned long long)(tg | u0);
            size_t eoff = (size_t)((t+1) & 1) * BB * HH + (size_t)(r0 + er) * HH + h0 + ec;
            store_sc0((unsigned long long*)(fsd + eoff), pay);          // fast (L2)
            __hip_atomic_store((unsigned long long*)(bkd + eoff), pay,
                               __ATOMIC_RELAXED, __HIP_MEMORY_SCOPE_AGENT); // backup (L3)
            *(unsigned*)(hs + ((size_t)(r0 + er) * TT + tok) * HH + h0 + ec) =
                u0 | (u1 << 16);
        }
        __syncthreads();   // drain: all waves' data stores ack'd in L2/L3
        if (tid == 0)
            store_u32_sc0(myflag, (unsigned)(t + 1));   // flag AFTER data drain
    }
}

// ---------------------------------------------------------------------------
// logits via MFMA: 64 tokens/block (4 waves x 16), K=1024, N=16 (9 used)
// ---------------------------------------------------------------------------
__global__ __launch_bounds__(256) void logits_kernel(
    const __hip_bfloat16* __restrict__ hs_f, const __hip_bfloat16* __restrict__ hs_b,
    const __hip_bfloat16* __restrict__ WdT, const float* __restrict__ bd,
    float* __restrict__ out)
{
    int n0 = blockIdx.x * 64;
    int wave = threadIdx.x >> 6, lane = threadIdx.x & 63;
    int lm = lane & 15, lk8 = (lane >> 4) * 8;
    int nw = n0 + wave * 16;
    const short8* af = (const short8*)(hs_f + (size_t)(nw + lm) * HH + lk8);
    const short8* ab = (const short8*)(hs_b + (size_t)(nw + lm) * HH + lk8);
    const short8* bw = (const short8*)(WdT + (size_t)lm * 1024 + lk8);
    floatx4 acc = {};
    #pragma unroll
    for (int kc = 0; kc < 16; ++kc) {
        acc = __builtin_amdgcn_mfma_f32_16x16x32_bf16(af[kc*4], bw[kc*4], acc, 0,0,0);
        acc = __builtin_amdgcn_mfma_f32_16x16x32_bf16(ab[kc*4], bw[(kc+16)*4], acc, 0,0,0);
    }
    if (lm < LL) {
        float bv = bd[lm];
        #pragma unroll
        for (int r = 0; r < 4; ++r) {
            int n = nw + (lane >> 4) * 4 + r;
            out[(size_t)n * LL + lm] = acc[r] + bv;
        }
    }
}

// ---------------------------------------------------------------------------
// CRF: fused lens + log-likelihood + Viterbi. One block/batch, 256 threads.
// ---------------------------------------------------------------------------
__global__ __launch_bounds__(256) void crf_kernel(
    const float* __restrict__ logits, const int* __restrict__ text,
    const int* __restrict__ labels, const float* __restrict__ trans,
    float* __restrict__ out_lens, float* __restrict__ out_ll,
    float* __restrict__ out_tags)
{
    int b = blockIdx.x, tid = threadIdx.x;
    const float* lg = logits + (size_t)b * TT * LL;
    const int* lab = labels + b * TT;

    __shared__ float lgs[TT * LL];
    __shared__ float trs[81];
    __shared__ unsigned char bps[255 * LL + 1];
    __shared__ float partial[256];
    __shared__ int ired[256];
    __shared__ float tagf[TT];

    for (int i = tid; i < TT * LL; i += 256) lgs[i] = lg[i];
    if (tid < 81) trs[tid] = trans[tid];
    ired[tid] = (text[b * TT + tid] != 0) ? 1 : 0;
    __syncthreads();
    for (int s = 128; s > 0; s >>= 1) {
        if (tid < s) ired[tid] += ired[tid + s];
        __syncthreads();
    }
    int len = ired[0];
    if (tid == 0) out_lens[b] = (float)len;

    float up = 0.f;
    for (int t = tid; t < TT; t += 256) {
        float m = (t < len) ? 1.f : 0.f;
        up += m * lgs[t * LL + lab[t]];
        if (t >= 1) up += m * trs[lab[t - 1] * LL + lab[t]];
    }
    partial[tid] = up;
    __syncthreads();
    for (int s = 128; s > 0; s >>= 1) {
        if (tid < s) partial[tid] += partial[tid + s];
        __syncthreads();
    }

    if (tid < 64) {
        int lane = tid;
        int j = (lane < LL) ? lane : 0;
        float trj[LL];
        #pragma unroll
        for (int i = 0; i < LL; ++i) trj[i] = trs[i * LL + j];
        float alpha = lgs[j];
        float vit = alpha;
        for (int t = 1; t < TT; ++t) {
            bool m = t < len;
            float lgv = lgs[t * LL + j];
            float ta[LL];
            float mx = -1e30f, bv = -1e30f; int bi = 0;
            #pragma unroll
            for (int i = 0; i < LL; ++i) {
                float av = __shfl(alpha, i);
                float vv = __shfl(vit, i);
                ta[i] = av + trj[i];
                mx = fmaxf(mx, ta[i]);
                float sv = vv + trj[i];
                if (sv > bv) { bv = sv; bi = i; }
            }
            float s = 0.f;
            #pragma unroll
            for (int i = 0; i < LL; ++i) s += __expf(ta[i] - mx);
            float newa = mx + __logf(s) + lgv;
            float newv = bv + lgv;
            if (m) { alpha = newa; vit = newv; }
            if (lane < LL) bps[(t - 1) * LL + lane] = (unsigned char)(m ? bi : lane);
        }
        float aX[LL], vX[LL];
        #pragma unroll
        for (int i = 0; i < LL; ++i) { aX[i] = __shfl(alpha, i); vX[i] = __shfl(vit, i); }
        if (lane == 0) {
            float mx = -1e30f;
            #pragma unroll
            for (int i = 0; i < LL; ++i) mx = fmaxf(mx, aX[i]);
            float s = 0.f;
            #pragma unroll
            for (int i = 0; i < LL; ++i) s += __expf(aX[i] - mx);
            out_ll[b] = partial[0] - (mx + __logf(s));

            float bvv = vX[0]; int last = 0;
            #pragma unroll
            for (int i = 1; i < LL; ++i) if (vX[i] > bvv) { bvv = vX[i]; last = i; }
            tagf[TT - 1] = (float)last;
            int tg = last;
            for (int s2 = TT - 2; s2 >= 0; --s2) {
                tg = bps[s2 * LL + tg];
                tagf[s2] = (float)tg;
            }
        }
    }
    __syncthreads();
    out_tags[b * TT + tid] = tagf[tid];
}

// ---------------------------------------------------------------------------
extern "C" void kernel_launch(void* const* d_in, const int* in_sizes, int n_in,
                              void* d_out, int out_size, void* d_ws, size_t ws_size,
                              hipStream_t stream)
{
    const int*   text  = (const int*)d_in[0];
    const int*   sent  = (const int*)d_in[1];
    const int*   labels= (const int*)d_in[2];
    const float* wemb  = (const float*)d_in[3];
    const float* semb  = (const float*)d_in[4];
    const float* Wk_f  = (const float*)d_in[5];
    const float* Wr_f  = (const float*)d_in[6];
    const float* b_f   = (const float*)d_in[7];
    const float* Wk_b  = (const float*)d_in[8];
    const float* Wr_b  = (const float*)d_in[9];
    const float* b_b   = (const float*)d_in[10];
    const float* Wd    = (const float*)d_in[11];
    const float* bd    = (const float*)d_in[12];
    const float* trans = (const float*)d_in[13];
    float* out = (float*)d_out;

    char* ws = (char*)d_ws;
    __hip_bfloat16* xz_f = (__hip_bfloat16*)(ws + XZF_OFF);
    __hip_bfloat16* xz_b = (__hip_bfloat16*)(ws + XZB_OFF);
    __hip_bfloat16* hs_f = (__hip_bfloat16*)(ws + HSF_OFF);
    __hip_bfloat16* hs_b = (__hip_bfloat16*)(ws + HSB_OFF);
    __hip_bfloat16* xg   = (__hip_bfloat16*)(ws + XG_OFF);
    __hip_bfloat16* WkT  = (__hip_bfloat16*)(ws + WKT_OFF);
    __hip_bfloat16* WrT  = (__hip_bfloat16*)(ws + WRT_OFF);
    unsigned*       bk   = (unsigned*)(ws + BK_OFF);
    unsigned*       fast = (unsigned*)(ws + FAST_OFF);
    unsigned*       flg  = (unsigned*)(ws + FLAGS_OFF);
    __hip_bfloat16* WdT  = (__hip_bfloat16*)(ws + WDT_OFF);

    prep_xg <<<NT,  256, 0, stream>>>(text, sent, wemb, semb, xg);
    transpose_w<<<dim3(G4/64, (KP+63)/64, 2), 256, 0, stream>>>(Wk_f, Wk_b, WkT, DD, KP);
    transpose_w<<<dim3(G4/64, HH/64, 2),      256, 0, stream>>>(Wr_f, Wr_b, WrT, HH, HH);
    // zero backup + fast + flags (tag/flag 0 == h(0) = 0)
    hipMemsetAsync(ws + BK_OFF, 0, 2 * EX_BYTES + 1024, stream);

    embed_gemm<<<dim3(NT/128, G4/64, 2), 256, 0, stream>>>(
        xg, WkT, b_f, b_b, xz_f, xz_b);

    {
        void* args[] = { (void*)&xz_f, (void*)&xz_b, (void*)&WrT,
                         (void*)&bk, (void*)&fast, (void*)&flg,
                         (void*)&hs_f, (void*)&hs_b };
        hipLaunchCooperativeKernel((const void*)lstm_coop, dim3(256), dim3(256),
                                   args, 0, stream);
    }

    prep_wdT<<<16, 256, 0, stream>>>(Wd, WdT);   // aliases dead xz_f
    logits_kernel<<<NT/64, 256, 0, stream>>>(hs_f, hs_b, WdT, bd, out + OUT_LOGITS);
    crf_kernel<<<BB, 256, 0, stream>>>(out + OUT_LOGITS, text, labels, trans,
                                       out + OUT_LENS, out + OUT_LL, out + OUT_TAGS);
}